// Round 7
// baseline (6276.701 us; speedup 1.0000x reference)
//
#include <hip/hip_runtime.h>
#include <hip/hip_bf16.h>

#define B_ 256
#define S_ 512
#define H_ 1024
#define C_ 10

typedef unsigned long long u64;
typedef __attribute__((ext_vector_type(8))) short s8v;      // 8 bf16 (4 VGPRs) - MFMA A/B frag
typedef __attribute__((ext_vector_type(4))) float f4v;      // MFMA C/D frag

// ---------------- workspace layout (bytes) ----------------
// [0, 16384)       : flags[4 groups][64 blocks][16 u32] — one 64 B line per block,
//                    u32 slots 0..3 = per-wave step counters. 1 poller/line (aggregator lane).
// [16384, 32768)   : mailbox[4][64][16 u32] — one 64 B line per consumer block,
//                    slot 0 = "h(t) ready". 4 pollers/line.
// [32768, +512K)   : xT  (S x B fp32)
// [+512K, +512K)   : h0  (B x H bf16), zeroed per launch
// [+512K, +512K)   : h1
// [+512K, +8M)     : Wp  (packed bf16 weights, fragment-linear, MFMA A operand)
#define HDR_ 32768

__global__ void prep_w(const float* __restrict__ wg, const float* __restrict__ wi,
                       const float* __restrict__ wf, const float* __restrict__ wo,
                       __hip_bfloat16* __restrict__ Wp) {
    int idx = blockIdx.x * 256 + threadIdx.x;        // 524288 groups of 8
    int g   = idx >> 17;
    int rem = idx & 131071;
    int o   = rem >> 7;                              // out col 0..1023
    int kg  = rem & 127;                             // k0 = kg*8
    const float* src = (g == 0 ? wg : g == 1 ? wi : g == 2 ? wf : wo) + o * H_ + kg * 8;
    int kc   = kg >> 2;
    int quad = kg & 3;
    int lane = quad * 16 + (o & 15);
    int ot   = o >> 4;
    int blk  = (g * 64 + ot) * 32 + kc;
    __hip_bfloat16* dst = Wp + blk * 512 + lane * 8;
#pragma unroll
    for (int j = 0; j < 8; ++j) dst[j] = __float2bfloat16(src[j]);
}

__global__ void prep_x(const float* __restrict__ x, float* __restrict__ xT) {
    int i = blockIdx.x * 256 + threadIdx.x;          // 131072
    int t = i >> 8, b = i & 255;
    xT[i] = x[b * S_ + t];
}

__device__ __forceinline__ float sigmoid_f(float x) { return 1.0f / (1.0f + __expf(-x)); }
__device__ __forceinline__ float tanh_f(float x)    { return 2.0f / (1.0f + __expf(-2.0f * x)) - 1.0f; }

__device__ __forceinline__ float bf2f(unsigned short u) {
    union { unsigned i; float f; } x; x.i = ((unsigned)u) << 16; return x.f;
}
__device__ __forceinline__ unsigned short f2bf(float f) {
    union { __hip_bfloat16 h; unsigned short s; } x; x.h = __float2bfloat16(f); return x.s;
}

__device__ __forceinline__ void waitcnt_vm0() { asm volatile("s_waitcnt vmcnt(0)" ::: "memory"); }

__global__ __launch_bounds__(320, 2) void lstm_main(
    const float* __restrict__ xT,
    const float* __restrict__ wgx, const float* __restrict__ wix,
    const float* __restrict__ wfx, const float* __restrict__ wox,
    const float* __restrict__ bg,  const float* __restrict__ bi,
    const float* __restrict__ bf,  const float* __restrict__ bo,
    const __hip_bfloat16* __restrict__ Wp,
    __hip_bfloat16* __restrict__ h0, __hip_bfloat16* __restrict__ h1,
    const float* __restrict__ wph, const float* __restrict__ bp,
    float* __restrict__ out,
    unsigned* __restrict__ flags, unsigned* __restrict__ mailbox)
{
    // weights LDS-stationary: 4 gates x 32 kc x 64 lanes x 16B = 128 KB
    __shared__ s8v Wlds[4 * 32 * 64];

    const int tid  = threadIdx.x;
    const int wgid = blockIdx.x;         // 256 blocks x 320 threads (5 waves)
    // XCD-affinity remap: group m lives on XCDs {2m, 2m+1} under round-robin dispatch
    const int m    = (wgid & 7) >> 1;                 // batch group 0..3 (64 rows)
    const int n    = ((wgid >> 3) << 1) | (wgid & 1); // out-tile 0..63 (16 cols/gate)
    const int w    = tid >> 6;           // wave 0..3 compute, wave 4 aggregator
    const int l    = tid & 63;

    // stage this block's weights into LDS (waves 0..3, coalesced 16B loads)
    if (w < 4) {
        const s8v* Wv = (const s8v*)Wp;
#pragma unroll
        for (int j = 0; j < 32; ++j) {
            int idx = j * 256 + tid;             // 0..8191
            int g   = idx >> 11;
            int rem = idx & 2047;                // kc*64 + lane
            Wlds[g * 2048 + rem] = Wv[((g * 64 + n) * 32) * 64 + rem];
        }
    }
    __syncthreads();                     // all 5 waves; the ONLY barrier in this kernel

    if (w == 4) {
        if (n != 0) return;              // one aggregator wave per group
        // aggregator for group m: lane j watches block j's flag line, fans out to
        // block j's private mailbox line.
        const u64* fb = (const u64*)flags + (size_t)m * 512 + l * 8;  // 2 u64 = 4 wave flags
        unsigned*  mb = mailbox + m * 1024 + l * 16;
        for (unsigned t = 1; t <= (unsigned)S_; ++t) {
            for (;;) {
                u64 a = __hip_atomic_load(fb,     __ATOMIC_RELAXED, __HIP_MEMORY_SCOPE_AGENT);
                u64 c = __hip_atomic_load(fb + 1, __ATOMIC_RELAXED, __HIP_MEMORY_SCOPE_AGENT);
                unsigned mn = min(min((unsigned)a, (unsigned)(a >> 32)),
                                  min((unsigned)c, (unsigned)(c >> 32)));
                if (__ballot(mn < t) == 0ull) break;
                __builtin_amdgcn_s_sleep(1);
            }
            __hip_atomic_store(mb, t, __ATOMIC_RELAXED, __HIP_MEMORY_SCOPE_AGENT);
        }
        return;
    }

    // ---- compute waves (0..3), fully independent: no intra-block barriers ----
    const int quad = l >> 4;
    const int l16  = l & 15;
    const int b    = m * 64 + w * 16 + l16;  // this lane's batch row (B-frag col / D col)
    const int out0 = n * 16 + quad * 4;      // first of this lane's 4 hidden cols (D rows)

    float wxg[4], wxi[4], wxf[4], wxo[4], bbg[4], bbi[4], bbf[4], bbo[4];
    *(float4*)wxg = *(const float4*)(wgx + out0);
    *(float4*)wxi = *(const float4*)(wix + out0);
    *(float4*)wxf = *(const float4*)(wfx + out0);
    *(float4*)wxo = *(const float4*)(wox + out0);
    *(float4*)bbg = *(const float4*)(bg + out0);
    *(float4*)bbi = *(const float4*)(bi + out0);
    *(float4*)bbf = *(const float4*)(bf + out0);
    *(float4*)bbo = *(const float4*)(bo + out0);

    float cs[4] = {0.f, 0.f, 0.f, 0.f};     // persistent cell state

    unsigned*       myflag = flags   + (m * 64 + n) * 16 + w;   // this wave's slot
    const unsigned* mymb   = mailbox + (m * 64 + n) * 16;       // block-private line

    for (int t = 0; t < S_; ++t) {
        const __hip_bfloat16* hin  = (t & 1) ? h1 : h0;
        __hip_bfloat16*       hout = (t & 1) ? h0 : h1;

        float xa = xT[t * B_ + b];           // independent of h

        // wait for h(t): private mailbox line, wave-uniform load, 4 pollers
        while (__hip_atomic_load(mymb, __ATOMIC_RELAXED, __HIP_MEMORY_SCOPE_AGENT) < (unsigned)t)
            __builtin_amdgcn_s_sleep(1);

        // preload all h B-fragments (LLC sc1 loads, pipelined)
        const u64* hb = (const u64*)hin + (size_t)b * 256 + quad * 2;
        u64 hq[64];
#pragma unroll
        for (int kc = 0; kc < 32; ++kc) {
            hq[2 * kc]     = __hip_atomic_load(hb + kc * 8,     __ATOMIC_RELAXED, __HIP_MEMORY_SCOPE_AGENT);
            hq[2 * kc + 1] = __hip_atomic_load(hb + kc * 8 + 1, __ATOMIC_RELAXED, __HIP_MEMORY_SCOPE_AGENT);
        }

        f4v acc0 = {0.f, 0.f, 0.f, 0.f}, acc1 = acc0, acc2 = acc0, acc3 = acc0;
#pragma unroll
        for (int kc = 0; kc < 32; ++kc) {
            union { u64 q[2]; s8v v; } hf_;
            hf_.q[0] = hq[2 * kc]; hf_.q[1] = hq[2 * kc + 1];
            s8v hv = hf_.v;
            acc0 = __builtin_amdgcn_mfma_f32_16x16x32_bf16(Wlds[0 * 2048 + kc * 64 + l], hv, acc0, 0, 0, 0);
            acc1 = __builtin_amdgcn_mfma_f32_16x16x32_bf16(Wlds[1 * 2048 + kc * 64 + l], hv, acc1, 0, 0, 0);
            acc2 = __builtin_amdgcn_mfma_f32_16x16x32_bf16(Wlds[2 * 2048 + kc * 64 + l], hv, acc2, 0, 0, 0);
            acc3 = __builtin_amdgcn_mfma_f32_16x16x32_bf16(Wlds[3 * 2048 + kc * 64 + l], hv, acc3, 0, 0, 0);
        }

        // epilogue: D row (quad*4+r) = hidden col out0+r, D col (l16) = batch b
        unsigned short hs[4];
#pragma unroll
        for (int r = 0; r < 4; ++r) {
            float pg = acc0[r] + xa * wxg[r] + bbg[r];
            float pi = acc1[r] + xa * wxi[r] + bbi[r];
            float pf = acc2[r] + xa * wxf[r] + bbf[r];
            float po = acc3[r] + xa * wxo[r] + bbo[r];
            float gv = tanh_f(pg);
            float iv = sigmoid_f(pi);
            float fv = sigmoid_f(pf);
            float ov = sigmoid_f(po);
            float cn = gv * iv + cs[r] * fv;
            cs[r] = cn;
            hs[r] = f2bf(tanh_f(cn) * ov);
        }
        union { unsigned short s[4]; u64 q; } hp_;
        hp_.s[0] = hs[0]; hp_.s[1] = hs[1]; hp_.s[2] = hs[2]; hp_.s[3] = hs[3];
        __hip_atomic_store((u64*)(hout + b * H_ + out0), hp_.q,
                           __ATOMIC_RELAXED, __HIP_MEMORY_SCOPE_AGENT);
        waitcnt_vm0();                       // this wave's h store ack'ed at LLC
        if (l == 0)
            __hip_atomic_store(myflag, (unsigned)(t + 1), __ATOMIC_RELAXED, __HIP_MEMORY_SCOPE_AGENT);
    }

    // wait for final h (in h0, t=511 odd wrote h0)
    while (__hip_atomic_load(mymb, __ATOMIC_RELAXED, __HIP_MEMORY_SCOPE_AGENT) < (unsigned)S_)
        __builtin_amdgcn_s_sleep(1);

    // projection restricted to own group's rows: out[row][cc], rows [64m, 64m+64)
    const __hip_bfloat16* hf = h0;
    int wig = n * 4 + w;                     // wave index in group, 0..255
    for (int p = wig; p < 64 * C_; p += 256) {
        int row = m * 64 + p / C_;
        int cc  = p % C_;
        const u64* hr = (const u64*)(hf + row * H_);
        const float* wr = wph + cc * H_;
        float acc = 0.f;
#pragma unroll
        for (int j = 0; j < 4; ++j) {
            int k = j * 256 + l * 4;
            u64 hv4 = __hip_atomic_load(hr + (k >> 2), __ATOMIC_RELAXED, __HIP_MEMORY_SCOPE_AGENT);
            union { u64 q; unsigned short s[4]; } u_; u_.q = hv4;
            float4 wv = *(const float4*)(wr + k);
            acc += bf2f(u_.s[0]) * wv.x + bf2f(u_.s[1]) * wv.y
                 + bf2f(u_.s[2]) * wv.z + bf2f(u_.s[3]) * wv.w;
        }
#pragma unroll
        for (int off = 32; off > 0; off >>= 1) acc += __shfl_down(acc, off, 64);
        if (l == 0) out[row * C_ + cc] = acc + bp[cc];
    }
}

extern "C" void kernel_launch(void* const* d_in, const int* in_sizes, int n_in,
                              void* d_out, int out_size, void* d_ws, size_t ws_size,
                              hipStream_t stream) {
    const float* xx  = (const float*)d_in[0];
    const float* wgx = (const float*)d_in[1];
    const float* wix = (const float*)d_in[2];
    const float* wfx = (const float*)d_in[3];
    const float* wox = (const float*)d_in[4];
    const float* wgh = (const float*)d_in[5];
    const float* wih = (const float*)d_in[6];
    const float* wfh = (const float*)d_in[7];
    const float* woh = (const float*)d_in[8];
    const float* wph = (const float*)d_in[9];
    const float* bg  = (const float*)d_in[10];
    const float* bi  = (const float*)d_in[11];
    const float* bf  = (const float*)d_in[12];
    const float* bo  = (const float*)d_in[13];
    const float* bp  = (const float*)d_in[14];
    float* out = (float*)d_out;

    char* ws = (char*)d_ws;
    unsigned*       flags   = (unsigned*)ws;                // 16 KB
    unsigned*       mailbox = (unsigned*)(ws + 16384);      // 16 KB
    float*          xT = (float*)(ws + HDR_);
    __hip_bfloat16* h0 = (__hip_bfloat16*)(ws + HDR_ + 524288);
    __hip_bfloat16* h1 = (__hip_bfloat16*)(ws + HDR_ + 2 * 524288);
    __hip_bfloat16* Wp = (__hip_bfloat16*)(ws + HDR_ + 3 * 524288);

    hipMemsetAsync(ws, 0, HDR_, stream);                  // flags + mailboxes = 0
    hipMemsetAsync(h0, 0, 524288, stream);                // h_0 = 0
    prep_x<<<512, 256, 0, stream>>>(xx, xT);
    prep_w<<<2048, 256, 0, stream>>>(wgh, wih, wfh, woh, Wp);
    lstm_main<<<256, 320, 0, stream>>>(xT, wgx, wix, wfx, wox, bg, bi, bf, bo,
                                       Wp, h0, h1, wph, bp, out, flags, mailbox);
}